// Round 1
// baseline (329.597 us; speedup 1.0000x reference)
//
#include <hip/hip_runtime.h>
#include <hip/hip_bf16.h>

#define NN 50000
#define NE 800000
#define NG 512
#define IND 128
#define MIDD 12

// ---------------- fold weights: W1eff=[256,12], b1eff, W2eff=[24,12], b2eff ----
__global__ void fold_kernel(const float* __restrict__ W1a, const float* __restrict__ b1a,
                            const float* __restrict__ W1b, const float* __restrict__ b1b,
                            const float* __restrict__ W2a, const float* __restrict__ b2a,
                            const float* __restrict__ W2b, const float* __restrict__ b2b,
                            float* __restrict__ W1eff, float* __restrict__ b1eff,
                            float* __restrict__ W2eff, float* __restrict__ b2eff) {
    int t = blockIdx.x * blockDim.x + threadIdx.x;
    if (t < 3072) {                       // W1eff[r][c], r<256, c<12
        int r = t / 12, c = t % 12;
        float acc = 0.f;
        for (int k = 0; k < 256; ++k) acc += W1a[r*256 + k] * W1b[k*12 + c];
        W1eff[r*12 + c] = acc;
    } else if (t < 3084) {                // b1eff
        int c = t - 3072;
        float acc = b1b[c];
        for (int k = 0; k < 256; ++k) acc += b1a[k] * W1b[k*12 + c];
        b1eff[c] = acc;
    } else if (t < 3372) {                // W2eff[r][c], r<24
        int u = t - 3084;
        int r = u / 12, c = u % 12;
        float acc = 0.f;
        for (int k = 0; k < 256; ++k) acc += W2a[r*256 + k] * W2b[k*12 + c];
        W2eff[r*12 + c] = acc;
    } else if (t < 3384) {                // b2eff
        int c = t - 3372;
        float acc = b2b[c];
        for (int k = 0; k < 256; ++k) acc += b2a[k] * W2b[k*12 + c];
        b2eff[c] = acc;
    }
}

// ---------------- p1: h [NN,128] @ W1eff -> p1_top [NN,12], p1_bot [NN,12] -----
__global__ void p1_kernel(const float* __restrict__ h, const float* __restrict__ W1eff,
                          float* __restrict__ p1t, float* __restrict__ p1b) {
    __shared__ float wsm[256 * 12];     // 12 KB
    __shared__ float hs[16 * 129];      // 16 rows, padded stride 129
    int tid = threadIdx.x;
    for (int i = tid; i < 3072; i += 256) wsm[i] = W1eff[i];
    int node0 = blockIdx.x * 16;
    for (int i = tid; i < 16 * 128; i += 256) {
        int nl = i >> 7, k = i & 127;
        int n = node0 + nl;
        hs[nl * 129 + k] = (n < NN) ? h[n * 128 + k] : 0.0f;
    }
    __syncthreads();
    for (int idx = tid; idx < 16 * 24; idx += 256) {
        int nl = idx / 24, c = idx % 24;
        int n = node0 + nl;
        if (n >= NN) continue;
        const float* hrow = &hs[nl * 129];
        float acc = 0.f;
        if (c < 12) {
            #pragma unroll
            for (int k = 0; k < 128; ++k) acc += hrow[k] * wsm[k*12 + c];
            p1t[n*12 + c] = acc;
        } else {
            int cc = c - 12;
            #pragma unroll
            for (int k = 0; k < 128; ++k) acc += hrow[k] * wsm[(128+k)*12 + cc];
            p1b[n*12 + cc] = acc;
        }
    }
}

// ---------------- edge scatter: acc[dst] += pbot[src], one thread per (e, c) ---
__global__ void edge_kernel(const int* __restrict__ src, const int* __restrict__ dst,
                            const float* __restrict__ pb, float* __restrict__ acc,
                            float* __restrict__ cnt) {
    int t = blockIdx.x * blockDim.x + threadIdx.x;
    if (t >= NE * 12) return;
    int e = t / 12;
    int c = t - e * 12;
    int s = src[e], d = dst[e];
    atomicAdd(&acc[d * 12 + c], pb[s * 12 + c]);
    if (cnt != nullptr && c == 0) atomicAdd(&cnt[d], 1.0f);
}

// ---------------- finalize layer1 + compute p2_top/p2_bot ----------------------
__global__ void finalize1_kernel(const float* __restrict__ p1t, const float* __restrict__ acc1,
                                 const float* __restrict__ cnt, const float* __restrict__ b1eff,
                                 const float* __restrict__ W2eff,
                                 float* __restrict__ p2t, float* __restrict__ p2b) {
    __shared__ float w2[288];
    __shared__ float b1[12];
    int tid = threadIdx.x;
    for (int i = tid; i < 288; i += 256) w2[i] = W2eff[i];
    if (tid < 12) b1[tid] = b1eff[tid];
    __syncthreads();
    int n = blockIdx.x * blockDim.x + tid;
    if (n >= NN) return;
    float c = cnt[n];
    float inv = c > 0.f ? 1.f / c : 0.f;
    float h1[12];
    #pragma unroll
    for (int j = 0; j < 12; ++j) {
        float v = p1t[n*12 + j] + acc1[n*12 + j] * inv + b1[j];
        h1[j] = v > 0.f ? v : 0.f;
    }
    #pragma unroll
    for (int co = 0; co < 12; ++co) {
        float a = 0.f, b = 0.f;
        #pragma unroll
        for (int k = 0; k < 12; ++k) {
            a += h1[k] * w2[k*12 + co];
            b += h1[k] * w2[(12+k)*12 + co];
        }
        p2t[n*12 + co] = a;
        p2b[n*12 + co] = b;
    }
}

// ---------------- finalize layer2 + graph pooling ------------------------------
__global__ void finalize2_kernel(const float* __restrict__ p2t, const float* __restrict__ acc2,
                                 const float* __restrict__ cnt, const float* __restrict__ b2eff,
                                 const int* __restrict__ graph_id,
                                 float* __restrict__ accg, float* __restrict__ cntg) {
    __shared__ float b2[12];
    if (threadIdx.x < 12) b2[threadIdx.x] = b2eff[threadIdx.x];
    __syncthreads();
    int n = blockIdx.x * blockDim.x + threadIdx.x;
    if (n >= NN) return;
    float c = cnt[n];
    float inv = c > 0.f ? 1.f / c : 0.f;
    int g = graph_id[n];
    #pragma unroll
    for (int j = 0; j < 12; ++j) {
        float v = p2t[n*12 + j] + acc2[n*12 + j] * inv + b2[j];
        v = v > 0.f ? v : 0.f;
        atomicAdd(&accg[g*12 + j], v);
    }
    atomicAdd(&cntg[g], 1.0f);
}

// ---------------- output: hg @ Wc + bc -----------------------------------------
__global__ void out_kernel(const float* __restrict__ accg, const float* __restrict__ cntg,
                           const float* __restrict__ Wc, const float* __restrict__ bc,
                           float* __restrict__ out) {
    int t = blockIdx.x * blockDim.x + threadIdx.x;
    if (t >= NG * 10) return;
    int g = t / 10, cls = t - g * 10;
    float c = cntg[g];
    float inv = c > 0.f ? 1.f / c : 0.f;
    float acc = bc[cls];
    #pragma unroll
    for (int j = 0; j < 12; ++j) acc += accg[g*12 + j] * inv * Wc[j*10 + cls];
    out[t] = acc;
}

extern "C" void kernel_launch(void* const* d_in, const int* in_sizes, int n_in,
                              void* d_out, int out_size, void* d_ws, size_t ws_size,
                              hipStream_t stream) {
    const float* h   = (const float*)d_in[0];
    const int* src   = (const int*)d_in[1];
    const int* dst   = (const int*)d_in[2];
    const int* gid   = (const int*)d_in[3];
    const float* W1a = (const float*)d_in[4];
    const float* b1a = (const float*)d_in[5];
    const float* W1b = (const float*)d_in[6];
    const float* b1b = (const float*)d_in[7];
    const float* W2a = (const float*)d_in[8];
    const float* b2a = (const float*)d_in[9];
    const float* W2b = (const float*)d_in[10];
    const float* b2b = (const float*)d_in[11];
    const float* Wc  = (const float*)d_in[12];
    const float* bc  = (const float*)d_in[13];
    float* out = (float*)d_out;

    float* ws = (float*)d_ws;
    float* W1eff = ws;                    // 3072
    float* b1eff = ws + 3072;             // 12
    float* W2eff = ws + 3084;             // 288
    float* b2eff = ws + 3372;             // 12
    float* p1t   = ws + 3384;             // 600000
    float* p1b   = ws + 603384;           // 600000
    float* p2t   = ws + 1203384;          // 600000
    float* p2b   = ws + 1803384;          // 600000
    float* acc1  = ws + 2403384;          // 600000  -- zeroed region starts here
    float* acc2  = ws + 3003384;          // 600000
    float* cnt   = ws + 3603384;          // 50000
    float* accg  = ws + 3653384;          // 6144
    float* cntg  = ws + 3659528;          // 512   -> total 3660040 floats (~14.6 MB)

    // zero all accumulators in one memset (contiguous)
    hipMemsetAsync(acc1, 0, (size_t)(600000 + 600000 + 50000 + 6144 + 512) * sizeof(float), stream);

    fold_kernel<<<14, 256, 0, stream>>>(W1a, b1a, W1b, b1b, W2a, b2a, W2b, b2b,
                                        W1eff, b1eff, W2eff, b2eff);

    p1_kernel<<<(NN + 15) / 16, 256, 0, stream>>>(h, W1eff, p1t, p1b);

    edge_kernel<<<(NE * 12 + 255) / 256, 256, 0, stream>>>(src, dst, p1b, acc1, cnt);

    finalize1_kernel<<<(NN + 255) / 256, 256, 0, stream>>>(p1t, acc1, cnt, b1eff, W2eff, p2t, p2b);

    edge_kernel<<<(NE * 12 + 255) / 256, 256, 0, stream>>>(src, dst, p2b, acc2, nullptr);

    finalize2_kernel<<<(NN + 255) / 256, 256, 0, stream>>>(p2t, acc2, cnt, b2eff, gid, accg, cntg);

    out_kernel<<<(NG * 10 + 255) / 256, 256, 0, stream>>>(accg, cntg, Wc, bc, out);
}